// Round 11
// baseline (254.318 us; speedup 1.0000x reference)
//
#include <hip/hip_runtime.h>
#include <cmath>

#define Bb 2048
#define Nn 128
#define Dd 64
#define Hh 128

typedef __attribute__((ext_vector_type(8))) short short8;
typedef __attribute__((ext_vector_type(4))) float f32x4;

__device__ __forceinline__ void ld4(float* d, const float* s) {
  const float4 v = *(const float4*)s;
  d[0] = v.x; d[1] = v.y; d[2] = v.z; d[3] = v.w;
}
__device__ __forceinline__ void st4(float* d, const float* s) {
  *(float4*)d = make_float4(s[0], s[1], s[2], s[3]);
}

// 2-way bf16 split, RNE lo: hi = round-half-up bf16 of v, lo = RNE bf16 of
// residual. Paired with the lo*lo MFMA term: split-product error ~2^-18.
__device__ __forceinline__ void splitf(float v, unsigned short& hi, unsigned short& lo) {
  const unsigned up = __float_as_uint(v) + 0x8000u;
  hi = (unsigned short)(up >> 16);
  const float hif = __uint_as_float(up & 0xffff0000u);
  unsigned ur = __float_as_uint(v - hif);
  ur += 0x7fffu + ((ur >> 16) & 1u);           // RNE
  lo = (unsigned short)(ur >> 16);
}

// Branch-free exact-GELU via Abramowitz-Stegun 7.1.26 (|erf err| <= 1.5e-7).
__device__ __forceinline__ float gelu_exact(float v) {
  const float s  = fabsf(v) * 0.70710678118654752f;
  const float tt = __builtin_amdgcn_rcpf(fmaf(0.3275911f, s, 1.0f));
  float p = fmaf(tt, 1.061405429f, -1.453152027f);
  p = fmaf(tt, p, 1.421413741f);
  p = fmaf(tt, p, -0.284496736f);
  p = fmaf(tt, p, 0.254829592f);
  p = p * tt;
  const float E  = exp2f(s * s * -1.44269504088896f);
  const float er = fmaf(-p, E, 1.0f);
  const float es = copysignf(er, v);
  return v * fmaf(0.5f, es, 0.5f);
}

// ---------------------------------------------------------------------------
// k_prep (grid Nn): fold enc/dec; fragment-pack W1 (A-frag, plain k-order) and
// Wfold (A-frag, PERMUTED k-order matching register-resident Hg B-frags);
// blocks 0-2 fragment-pack conn[d] (bf16-exact 0/1).
// ---------------------------------------------------------------------------
__global__ __launch_bounds__(256)
void k_prep(const float* __restrict__ W1, const float* __restrict__ W2,
            const float* __restrict__ b2, const float* __restrict__ encW,
            const float* __restrict__ encb, const float* __restrict__ decW,
            const float* __restrict__ conn,
            unsigned short* __restrict__ W1pHi, unsigned short* __restrict__ W1pLo,
            unsigned short* __restrict__ WfpHi, unsigned short* __restrict__ WfpLo,
            float* __restrict__ bfold, unsigned short* __restrict__ connP) {
  __shared__ float sm[26112];                  // 104.4 KB
  float* decS = sm;                            // [64][68]
  float* E2s  = sm + 4352;                     // [64][68]
  float* W2s  = sm + 8704;                     // [128][68]
  float* Wfs  = sm + 17408;                    // [128][68]
  float* W1s  = sm;                            // [64][132] overlays decS+E2s
  const int n = blockIdx.x, t = threadIdx.x;

  // phase 1: stage decW, W2[n]
  #pragma unroll
  for (int i = 0; i < 4; ++i) {
    const int fi = t + i * 256;
    *(float4*)&decS[(fi >> 4) * 68 + (fi & 15) * 4] = *(const float4*)(decW + fi * 4);
  }
  #pragma unroll
  for (int i = 0; i < 8; ++i) {
    const int fi = t + i * 256;
    *(float4*)&W2s[(fi >> 4) * 68 + (fi & 15) * 4] =
        *(const float4*)(W2 + (size_t)n * 8192 + fi * 4);
  }
  __syncthreads();

  // phase 2: E2 = encW @ decW
  {
    const int d = t >> 2, f0 = (t & 3) * 16;
    float acc[16];
    #pragma unroll
    for (int ff = 0; ff < 16; ++ff) acc[ff] = 0.f;
    for (int e = 0; e < 64; ++e) {
      const float a = encW[d * 64 + e];
      #pragma unroll
      for (int ff = 0; ff < 16; ++ff) acc[ff] += a * decS[e * 68 + f0 + ff];
    }
    #pragma unroll
    for (int q = 0; q < 4; ++q) st4(&E2s[d * 68 + f0 + q * 4], &acc[q * 4]);
  }
  __syncthreads();

  // phase 3: Wfs = W2s @ E2s; bfold
  {
    const int h = t >> 1, f0 = (t & 1) * 32;
    float acc[32];
    #pragma unroll
    for (int ff = 0; ff < 32; ++ff) acc[ff] = 0.f;
    for (int d2 = 0; d2 < 64; ++d2) {
      const float a = W2s[h * 68 + d2];
      #pragma unroll
      for (int q = 0; q < 8; ++q) {
        float e4[4]; ld4(e4, &E2s[d2 * 68 + f0 + q * 4]);
        #pragma unroll
        for (int r = 0; r < 4; ++r) acc[q * 4 + r] += a * e4[r];
      }
    }
    #pragma unroll
    for (int q = 0; q < 8; ++q) st4(&Wfs[h * 68 + f0 + q * 4], &acc[q * 4]);
  }
  if (t < 64) {
    float s = 0.f;
    for (int e = 0; e < 64; ++e) s += encb[e] * decS[e * 68 + t];
    for (int d2 = 0; d2 < 64; ++d2) s += b2[n * 64 + d2] * E2s[d2 * 68 + t];
    bfold[n * 64 + t] = s;
  }
  __syncthreads();

  // phase 4: pack Wfs -> Wfp (A-frag with PERMUTED k); stage W1 -> W1s
  #pragma unroll
  for (int rep = 0; rep < 4; ++rep) {
    const int idx = rep * 256 + t;
    const int ft = idx >> 8, kc = (idx >> 6) & 3, ll = idx & 63;
    const int f = ft * 16 + (ll & 15);
    short8 vh, vl;
    #pragma unroll
    for (int j = 0; j < 8; ++j) {
      const int hcol = kc * 32 + ((j >> 2) << 4) + ((ll >> 4) << 2) + (j & 3);
      unsigned short hi, lo; splitf(Wfs[hcol * 68 + f], hi, lo);
      vh[j] = (short)hi; vl[j] = (short)lo;
    }
    const size_t o = (((size_t)n * 4 + ft) * 4 + kc) * 512 + (size_t)ll * 8;
    *(short8*)(WfpHi + o) = vh;
    *(short8*)(WfpLo + o) = vl;
  }
  #pragma unroll
  for (int i = 0; i < 8; ++i) {
    const int fi = t + i * 256;
    *(float4*)&W1s[(fi >> 5) * 132 + (fi & 31) * 4] =
        *(const float4*)(W1 + (size_t)n * 8192 + fi * 4);
  }
  __syncthreads();

  // phase 5: pack W1s -> W1p (A-frag, plain k-order)
  #pragma unroll
  for (int rep = 0; rep < 4; ++rep) {
    const int idx = rep * 256 + t;
    const int mt = idx >> 7, c2 = (idx >> 6) & 1, ll = idx & 63;
    const int col = mt * 16 + (ll & 15), k0 = c2 * 32 + (ll >> 4) * 8;
    short8 vh, vl;
    #pragma unroll
    for (int j = 0; j < 8; ++j) {
      unsigned short hi, lo; splitf(W1s[(k0 + j) * 132 + col], hi, lo);
      vh[j] = (short)hi; vl[j] = (short)lo;
    }
    const size_t o = (((size_t)n * 8 + mt) * 2 + c2) * 512 + (size_t)ll * 8;
    *(short8*)(W1pHi + o) = vh;
    *(short8*)(W1pLo + o) = vl;
  }

  // phase 6 (blocks 0-2): fragment-pack conn[n] (A-frags, bf16-exact 0/1)
  if (n < 3) {
    #pragma unroll
    for (int rep = 0; rep < 8; ++rep) {
      const int slot = rep * 256 + t;            // 2048 lane-slots
      const int rt = slot >> 8, kc = (slot >> 6) & 3, ll = slot & 63;
      const int i = rt * 16 + (ll & 15), j0 = kc * 32 + (ll >> 4) * 8;
      const float* cp = conn + (size_t)n * 16384 + i * 128 + j0;
      float cv[8];
      ld4(cv, cp); ld4(cv + 4, cp + 4);
      short8 v;
      #pragma unroll
      for (int j = 0; j < 8; ++j)
        v[j] = (short)(__float_as_uint(cv[j]) >> 16);   // 0.0/1.0 exact
      *(short8*)(connP + (((size_t)(n * 8 + rt)) * 4 + kc) * 512 + (size_t)ll * 8) = v;
    }
  }
}

// ---------------------------------------------------------------------------
// Kernel A (1 b-tile/wave + LDS-staged weights): ~112 total regs -> 4
// waves/SIMD (vs 2-b-tile's ~176 -> 2). Fragment reads = ds_read_b128 with
// immediate offsets; LDS region time-multiplexed W1 -> Wf -> mdL transpose.
// Math identical to round 9/10 (4-term split products, RNE lo).
// ---------------------------------------------------------------------------
template<bool SPLITIN>
__global__ __launch_bounds__(256)
void k_mlp(const float* __restrict__ xin, const unsigned short* __restrict__ xHi,
           const unsigned short* __restrict__ xLo,
           const unsigned short* __restrict__ W1pHi, const unsigned short* __restrict__ W1pLo,
           const float* __restrict__ b1, const float* __restrict__ lng,
           const float* __restrict__ lnb,
           const unsigned short* __restrict__ WfpHi, const unsigned short* __restrict__ WfpLo,
           const float* __restrict__ bfold, unsigned* __restrict__ mdP) {
  // [0,32KB): weight frags (hi @0, lo @16KB); later mdL overlays (17.4KB).
  // +448 u32 = 1792B bias region (b1[128], lng[128], lnb[128], bfold[64]).
  __shared__ __align__(16) unsigned ldsbuf[8192 + 448];
  float* bS = (float*)(ldsbuf + 8192);

  const int t = threadIdx.x;
  const int w = t >> 6, l = t & 63;
  const int bhat = l & 15, lg = l >> 4, kb = lg * 8;
  // XCD-bijective block swizzle: 4096 blocks, 8 XCDs -> 16 contiguous nodes/XCD
  const int wg = blockIdx.x;
  const int n  = (wg & 7) * 16 + ((wg >> 3) >> 5);
  const int b0 = ((wg >> 3) & 31) * 64;
  const int brow = b0 + w * 16 + bhat;         // this lane's batch row

  // ---- stage W1 frags + biases; coalesced uint4 copies ----
  {
    const uint4* whG = (const uint4*)(W1pHi + (size_t)n * 8192);
    const uint4* wlG = (const uint4*)(W1pLo + (size_t)n * 8192);
    uint4* lp = (uint4*)ldsbuf;
    #pragma unroll
    for (int i = 0; i < 4; ++i) {
      const int u4 = t + i * 256;              // 0..1023
      lp[u4]        = whG[u4];
      lp[1024 + u4] = wlG[u4];
    }
    if (t < 128) {
      bS[t]       = b1[n * Hh + t];
      bS[128 + t] = lng[n * Hh + t];
      bS[256 + t] = lnb[n * Hh + t];
    } else if (t < 192) {
      bS[384 + (t - 128)] = bfold[n * Dd + (t - 128)];
    }
  }

  // ---- x B-fragments (overlaps staging latency) ----
  short8 xhi[2], xlo[2];                       // [c2]
  {
    const size_t rowoff = ((size_t)brow * Nn + n) * Dd;
    if (SPLITIN) {
      const float* xr = xin + rowoff;
      #pragma unroll
      for (int c2 = 0; c2 < 2; ++c2) {
        const float4 p0 = *(const float4*)(xr + c2 * 32 + kb);
        const float4 p1 = *(const float4*)(xr + c2 * 32 + kb + 4);
        const float vv[8] = {p0.x, p0.y, p0.z, p0.w, p1.x, p1.y, p1.z, p1.w};
        #pragma unroll
        for (int j = 0; j < 8; ++j) {
          unsigned short hi, lo; splitf(vv[j], hi, lo);
          xhi[c2][j] = (short)hi; xlo[c2][j] = (short)lo;
        }
      }
    } else {
      const unsigned short* xh = xHi + rowoff;
      const unsigned short* xl = xLo + rowoff;
      #pragma unroll
      for (int c2 = 0; c2 < 2; ++c2) {
        xhi[c2] = *(const short8*)(xh + c2 * 32 + kb);
        xlo[c2] = *(const short8*)(xl + c2 * 32 + kb);
      }
    }
  }
  __syncthreads();

  const unsigned short* lw = (const unsigned short*)ldsbuf;

  // ---- GEMM1: acc[mt]; 4-term split product, smallest term first ----
  f32x4 acc[8];
  #pragma unroll
  for (int mt = 0; mt < 8; ++mt) {
    float b4[4]; ld4(b4, bS + mt * 16 + lg * 4);
    acc[mt] = (f32x4){b4[0], b4[1], b4[2], b4[3]};
  }
  #pragma unroll
  for (int mt = 0; mt < 8; ++mt) {
    #pragma unroll
    for (int c2 = 0; c2 < 2; ++c2) {
      const int fo = (mt * 2 + c2) * 512;      // u16 units; imm offset in ds_read
      const short8 ah = *(const short8*)(lw + fo + l * 8);
      const short8 al = *(const short8*)(lw + 8192 + fo + l * 8);
      acc[mt] = __builtin_amdgcn_mfma_f32_16x16x32_bf16(al, xlo[c2], acc[mt], 0, 0, 0);
      acc[mt] = __builtin_amdgcn_mfma_f32_16x16x32_bf16(al, xhi[c2], acc[mt], 0, 0, 0);
      acc[mt] = __builtin_amdgcn_mfma_f32_16x16x32_bf16(ah, xlo[c2], acc[mt], 0, 0, 0);
      acc[mt] = __builtin_amdgcn_mfma_f32_16x16x32_bf16(ah, xhi[c2], acc[mt], 0, 0, 0);
    }
  }
  __syncthreads();                             // all waves done reading W1 frags

  // ---- restage: Wf frags into the same region ----
  {
    const uint4* fhG = (const uint4*)(WfpHi + (size_t)n * 8192);
    const uint4* flG = (const uint4*)(WfpLo + (size_t)n * 8192);
    uint4* lp = (uint4*)ldsbuf;
    #pragma unroll
    for (int i = 0; i < 4; ++i) {
      const int u4 = t + i * 256;
      lp[u4]        = fhG[u4];
      lp[1024 + u4] = flG[u4];
    }
  }

  // ---- LayerNorm stats: per-lane 32 values + 2 shfl (overlaps restage) ----
  float sm = 0.f, sq = 0.f;
  #pragma unroll
  for (int mt = 0; mt < 8; ++mt)
    #pragma unroll
    for (int r = 0; r < 4; ++r) { const float v = acc[mt][r]; sm += v; sq += v * v; }
  sm += __shfl_xor(sm, 16); sq += __shfl_xor(sq, 16);
  sm += __shfl_xor(sm, 32); sq += __shfl_xor(sq, 32);
  const float mu = sm * (1.f / Hh);
  const float rs = rsqrtf(sq * (1.f / Hh) - mu * mu + 1e-5f);
  __syncthreads();

  // ---- GEMM2 (fused): per kc build Hg B-frag in-register, 4-term products ----
  f32x4 acc2[4];
  #pragma unroll
  for (int ft = 0; ft < 4; ++ft) {
    float b4[4]; ld4(b4, bS + 384 + ft * 16 + lg * 4);
    acc2[ft] = (f32x4){b4[0], b4[1], b4[2], b4[3]};
  }
  #pragma unroll
  for (int kc = 0; kc < 4; ++kc) {
    short8 hh, hl;
    #pragma unroll
    for (int half = 0; half < 2; ++half) {
      const int mt = kc * 2 + half;
      float g4[4], bb4[4];
      ld4(g4,  bS + 128 + mt * 16 + lg * 4);
      ld4(bb4, bS + 256 + mt * 16 + lg * 4);
      #pragma unroll
      for (int r = 0; r < 4; ++r) {
        const float v = gelu_exact((acc[mt][r] - mu) * rs * g4[r] + bb4[r]);
        unsigned short hi, lo; splitf(v, hi, lo);
        hh[half * 4 + r] = (short)hi;
        hl[half * 4 + r] = (short)lo;
      }
    }
    #pragma unroll
    for (int ft = 0; ft < 4; ++ft) {
      const int fo = (ft * 4 + kc) * 512;
      const short8 fh = *(const short8*)(lw + fo + l * 8);
      const short8 fl = *(const short8*)(lw + 8192 + fo + l * 8);
      acc2[ft] = __builtin_amdgcn_mfma_f32_16x16x32_bf16(fl, hl, acc2[ft], 0, 0, 0);
      acc2[ft] = __builtin_amdgcn_mfma_f32_16x16x32_bf16(fl, hh, acc2[ft], 0, 0, 0);
      acc2[ft] = __builtin_amdgcn_mfma_f32_16x16x32_bf16(fh, hl, acc2[ft], 0, 0, 0);
      acc2[ft] = __builtin_amdgcn_mfma_f32_16x16x32_bf16(fh, hh, acc2[ft], 0, 0, 0);
    }
  }
  __syncthreads();                             // done reading Wf frags

  // ---- md store: per-wave LDS transpose (overlays weight region) ----
  unsigned* mw = ldsbuf + w * (16 * 68);
  #pragma unroll
  for (int ft = 0; ft < 4; ++ft) {
    unsigned q[4];
    #pragma unroll
    for (int r = 0; r < 4; ++r) {
      unsigned short hi, lo; splitf(acc2[ft][r], hi, lo);
      q[r] = ((unsigned)hi << 16) | lo;
    }
    *(uint4*)&mw[bhat * 68 + ft * 16 + lg * 4] = *(const uint4*)q;
  }
  __syncthreads();
  #pragma unroll
  for (int i = 0; i < 4; ++i) {
    const int row = i * 4 + lg;                // local batch row 0..15
    const uint4 v = *(const uint4*)&mw[row * 68 + bhat * 4];
    *(uint4*)&mdP[((size_t)(b0 + w * 16 + row) * Nn + n) * Dd + bhat * 4] = v;
  }
}

// ---------------------------------------------------------------------------
// Kernel B (MFMA): x[b] = conn @ md[b] + decb.  conn is bf16-EXACT so the
// 2-term (bh, bl) product is the full precision product.
// LAST: write fp32 to d_out; else write bf16 hi/lo planes (aliased in d_out).
// ---------------------------------------------------------------------------
template<bool LAST>
__global__ __launch_bounds__(256)
void k_conn(const unsigned* __restrict__ mdP, const unsigned short* __restrict__ connP,
            const float* __restrict__ decb, unsigned short* __restrict__ xHi,
            unsigned short* __restrict__ xLo, float* __restrict__ xout) {
  __shared__ unsigned tl[128 * 65];            // 33.3 KB
  const int b = blockIdx.x, t = threadIdx.x;
  const int w = t >> 6, l = t & 63, lr = l & 15, lg = l >> 4;

  // stage md[b] transposed-addressable: tl[j*65 + e]
  const unsigned* mb = mdP + (size_t)b * (Nn * Dd);
  #pragma unroll
  for (int i = 0; i < 8; ++i) {
    const int fi = t + i * 256;                // uint4 index 0..2047
    const int j = fi >> 4, e0 = (fi & 15) * 4;
    const uint4 v = *(const uint4*)(mb + (size_t)fi * 4);
    unsigned* dp = &tl[j * 65 + e0];
    dp[0] = v.x; dp[1] = v.y; dp[2] = v.z; dp[3] = v.w;
  }
  __syncthreads();

  f32x4 acc[2][4];
  #pragma unroll
  for (int et = 0; et < 4; ++et) {
    const float dv = decb[et * 16 + lr];
    acc[0][et] = (f32x4){dv, dv, dv, dv};
    acc[1][et] = acc[0][et];
  }

  #pragma unroll
  for (int kc = 0; kc < 4; ++kc) {
    const short8 a0 = *(const short8*)(connP + ((size_t)(w * 2 + 0) * 4 + kc) * 512 + (size_t)l * 8);
    const short8 a1 = *(const short8*)(connP + ((size_t)(w * 2 + 1) * 4 + kc) * 512 + (size_t)l * 8);
    #pragma unroll
    for (int et = 0; et < 4; ++et) {
      const unsigned* tp = &tl[(kc * 32 + lg * 8) * 65 + et * 16 + lr];
      unsigned u[8];
      #pragma unroll
      for (int j = 0; j < 8; ++j) u[j] = tp[j * 65];
      short8 bh, bl;
      #pragma unroll
      for (int j = 0; j < 8; ++j) {
        bh[j] = (short)(u[j] >> 16);
        bl[j] = (short)(u[j] & 0xffffu);
      }
      acc[0][et] = __builtin_amdgcn_mfma_f32_16x16x32_bf16(a0, bl, acc[0][et], 0, 0, 0);
      acc[1][et] = __builtin_amdgcn_mfma_f32_16x16x32_bf16(a1, bl, acc[1][et], 0, 0, 0);
      acc[0][et] = __builtin_amdgcn_mfma_f32_16x16x32_bf16(a0, bh, acc[0][et], 0, 0, 0);
      acc[1][et] = __builtin_amdgcn_mfma_f32_16x16x32_bf16(a1, bh, acc[1][et], 0, 0, 0);
    }
  }

  #pragma unroll
  for (int rt = 0; rt < 2; ++rt) {
    #pragma unroll
    for (int et = 0; et < 4; ++et) {
      #pragma unroll
      for (int r = 0; r < 4; ++r) {
        const int i = w * 32 + rt * 16 + lg * 4 + r;
        const int e = et * 16 + lr;
        const size_t o = ((size_t)b * Nn + i) * Dd + e;
        if (LAST) {
          xout[o] = acc[rt][et][r];
        } else {
          unsigned short hi, lo; splitf(acc[rt][et][r], hi, lo);
          xHi[o] = hi; xLo[o] = lo;
        }
      }
    }
  }
}

extern "C" void kernel_launch(void* const* d_in, const int* in_sizes, int n_in,
                              void* d_out, int out_size, void* d_ws, size_t ws_size,
                              hipStream_t stream) {
  const float* x0   = (const float*)d_in[0];
  const float* W1   = (const float*)d_in[1];
  const float* b1   = (const float*)d_in[2];
  const float* lng  = (const float*)d_in[3];
  const float* lnb  = (const float*)d_in[4];
  const float* W2   = (const float*)d_in[5];
  const float* b2   = (const float*)d_in[6];
  const float* encW = (const float*)d_in[7];
  const float* encb = (const float*)d_in[8];
  const float* decW = (const float*)d_in[9];
  const float* decb = (const float*)d_in[10];
  const float* conn = (const float*)d_in[11];

  char* ws = (char*)d_ws;
  unsigned* mdP = (unsigned*)ws;                        // 64 MB
  size_t off = 64ull << 20;
  unsigned short* W1pHi = (unsigned short*)(ws + off); off += 2ull << 20;
  unsigned short* W1pLo = (unsigned short*)(ws + off); off += 2ull << 20;
  unsigned short* WfpHi = (unsigned short*)(ws + off); off += 2ull << 20;
  unsigned short* WfpLo = (unsigned short*)(ws + off); off += 2ull << 20;
  float* bfold = (float*)(ws + off); off += 128 * 64 * 4;
  unsigned short* connP = (unsigned short*)(ws + off); off += 3ull * 16384 * 2;

  // bf16 hi/lo planes for intermediate x, aliased into d_out (2*32MB = 64MB)
  unsigned short* xHi = (unsigned short*)d_out;
  unsigned short* xLo = xHi + (size_t)Bb * Nn * Dd;

  k_prep<<<Nn, 256, 0, stream>>>(W1, W2, b2, encW, encb, decW, conn,
                                 W1pHi, W1pLo, WfpHi, WfpLo, bfold, connP);

  k_mlp<true><<<4096, 256, 0, stream>>>(x0, nullptr, nullptr, W1pHi, W1pLo,
                                        b1, lng, lnb, WfpHi, WfpLo, bfold, mdP);
  k_conn<false><<<Bb, 256, 0, stream>>>(mdP, connP, decb, xHi, xLo, nullptr);

  k_mlp<false><<<4096, 256, 0, stream>>>(nullptr, xHi, xLo, W1pHi, W1pLo,
                                         b1, lng, lnb, WfpHi, WfpLo, bfold, mdP);
  k_conn<false><<<Bb, 256, 0, stream>>>(mdP, connP + 16384, decb, xHi, xLo, nullptr);

  k_mlp<false><<<4096, 256, 0, stream>>>(nullptr, xHi, xLo, W1pHi, W1pLo,
                                         b1, lng, lnb, WfpHi, WfpLo, bfold, mdP);
  k_conn<true><<<Bb, 256, 0, stream>>>(mdP, connP + 32768, decb, nullptr, nullptr,
                                       (float*)d_out);
}

// Round 13
// 247.350 us; speedup vs baseline: 1.0282x; 1.0282x over previous
//
#include <hip/hip_runtime.h>
#include <cmath>

#define Bb 2048
#define Nn 128
#define Dd 64
#define Hh 128

typedef __attribute__((ext_vector_type(8))) short short8;
typedef __attribute__((ext_vector_type(4))) float f32x4;

__device__ __forceinline__ void ld4(float* d, const float* s) {
  const float4 v = *(const float4*)s;
  d[0] = v.x; d[1] = v.y; d[2] = v.z; d[3] = v.w;
}
__device__ __forceinline__ void st4(float* d, const float* s) {
  *(float4*)d = make_float4(s[0], s[1], s[2], s[3]);
}

// 2-way bf16 split, RNE lo: hi = round-half-up bf16 of v, lo = RNE bf16 of
// residual. Paired with the lo*lo MFMA term: split-product error ~2^-18.
__device__ __forceinline__ void splitf(float v, unsigned short& hi, unsigned short& lo) {
  const unsigned up = __float_as_uint(v) + 0x8000u;
  hi = (unsigned short)(up >> 16);
  const float hif = __uint_as_float(up & 0xffff0000u);
  unsigned ur = __float_as_uint(v - hif);
  ur += 0x7fffu + ((ur >> 16) & 1u);           // RNE
  lo = (unsigned short)(ur >> 16);
}

// Branch-free exact-GELU via Abramowitz-Stegun 7.1.26 (|erf err| <= 1.5e-7).
__device__ __forceinline__ float gelu_exact(float v) {
  const float s  = fabsf(v) * 0.70710678118654752f;
  const float tt = __builtin_amdgcn_rcpf(fmaf(0.3275911f, s, 1.0f));
  float p = fmaf(tt, 1.061405429f, -1.453152027f);
  p = fmaf(tt, p, 1.421413741f);
  p = fmaf(tt, p, -0.284496736f);
  p = fmaf(tt, p, 0.254829592f);
  p = p * tt;
  const float E  = exp2f(s * s * -1.44269504088896f);
  const float er = fmaf(-p, E, 1.0f);
  const float es = copysignf(er, v);
  return v * fmaf(0.5f, es, 0.5f);
}

// ---------------------------------------------------------------------------
// k_prep (grid Nn): fold enc/dec; fragment-pack W1 (A-frag, plain k-order) and
// Wfold (A-frag, PERMUTED k-order matching register-resident Hg B-frags);
// blocks 0-2 fragment-pack conn[d] (bf16-exact 0/1).  [identical to r11]
// ---------------------------------------------------------------------------
__global__ __launch_bounds__(256)
void k_prep(const float* __restrict__ W1, const float* __restrict__ W2,
            const float* __restrict__ b2, const float* __restrict__ encW,
            const float* __restrict__ encb, const float* __restrict__ decW,
            const float* __restrict__ conn,
            unsigned short* __restrict__ W1pHi, unsigned short* __restrict__ W1pLo,
            unsigned short* __restrict__ WfpHi, unsigned short* __restrict__ WfpLo,
            float* __restrict__ bfold, unsigned short* __restrict__ connP) {
  __shared__ float sm[26112];                  // 104.4 KB
  float* decS = sm;                            // [64][68]
  float* E2s  = sm + 4352;                     // [64][68]
  float* W2s  = sm + 8704;                     // [128][68]
  float* Wfs  = sm + 17408;                    // [128][68]
  float* W1s  = sm;                            // [64][132] overlays decS+E2s
  const int n = blockIdx.x, t = threadIdx.x;

  // phase 1: stage decW, W2[n]
  #pragma unroll
  for (int i = 0; i < 4; ++i) {
    const int fi = t + i * 256;
    *(float4*)&decS[(fi >> 4) * 68 + (fi & 15) * 4] = *(const float4*)(decW + fi * 4);
  }
  #pragma unroll
  for (int i = 0; i < 8; ++i) {
    const int fi = t + i * 256;
    *(float4*)&W2s[(fi >> 4) * 68 + (fi & 15) * 4] =
        *(const float4*)(W2 + (size_t)n * 8192 + fi * 4);
  }
  __syncthreads();

  // phase 2: E2 = encW @ decW
  {
    const int d = t >> 2, f0 = (t & 3) * 16;
    float acc[16];
    #pragma unroll
    for (int ff = 0; ff < 16; ++ff) acc[ff] = 0.f;
    for (int e = 0; e < 64; ++e) {
      const float a = encW[d * 64 + e];
      #pragma unroll
      for (int ff = 0; ff < 16; ++ff) acc[ff] += a * decS[e * 68 + f0 + ff];
    }
    #pragma unroll
    for (int q = 0; q < 4; ++q) st4(&E2s[d * 68 + f0 + q * 4], &acc[q * 4]);
  }
  __syncthreads();

  // phase 3: Wfs = W2s @ E2s; bfold
  {
    const int h = t >> 1, f0 = (t & 1) * 32;
    float acc[32];
    #pragma unroll
    for (int ff = 0; ff < 32; ++ff) acc[ff] = 0.f;
    for (int d2 = 0; d2 < 64; ++d2) {
      const float a = W2s[h * 68 + d2];
      #pragma unroll
      for (int q = 0; q < 8; ++q) {
        float e4[4]; ld4(e4, &E2s[d2 * 68 + f0 + q * 4]);
        #pragma unroll
        for (int r = 0; r < 4; ++r) acc[q * 4 + r] += a * e4[r];
      }
    }
    #pragma unroll
    for (int q = 0; q < 8; ++q) st4(&Wfs[h * 68 + f0 + q * 4], &acc[q * 4]);
  }
  if (t < 64) {
    float s = 0.f;
    for (int e = 0; e < 64; ++e) s += encb[e] * decS[e * 68 + t];
    for (int d2 = 0; d2 < 64; ++d2) s += b2[n * 64 + d2] * E2s[d2 * 68 + t];
    bfold[n * 64 + t] = s;
  }
  __syncthreads();

  // phase 4: pack Wfs -> Wfp (A-frag with PERMUTED k); stage W1 -> W1s
  #pragma unroll
  for (int rep = 0; rep < 4; ++rep) {
    const int idx = rep * 256 + t;
    const int ft = idx >> 8, kc = (idx >> 6) & 3, ll = idx & 63;
    const int f = ft * 16 + (ll & 15);
    short8 vh, vl;
    #pragma unroll
    for (int j = 0; j < 8; ++j) {
      const int hcol = kc * 32 + ((j >> 2) << 4) + ((ll >> 4) << 2) + (j & 3);
      unsigned short hi, lo; splitf(Wfs[hcol * 68 + f], hi, lo);
      vh[j] = (short)hi; vl[j] = (short)lo;
    }
    const size_t o = (((size_t)n * 4 + ft) * 4 + kc) * 512 + (size_t)ll * 8;
    *(short8*)(WfpHi + o) = vh;
    *(short8*)(WfpLo + o) = vl;
  }
  #pragma unroll
  for (int i = 0; i < 8; ++i) {
    const int fi = t + i * 256;
    *(float4*)&W1s[(fi >> 5) * 132 + (fi & 31) * 4] =
        *(const float4*)(W1 + (size_t)n * 8192 + fi * 4);
  }
  __syncthreads();

  // phase 5: pack W1s -> W1p (A-frag, plain k-order)
  #pragma unroll
  for (int rep = 0; rep < 4; ++rep) {
    const int idx = rep * 256 + t;
    const int mt = idx >> 7, c2 = (idx >> 6) & 1, ll = idx & 63;
    const int col = mt * 16 + (ll & 15), k0 = c2 * 32 + (ll >> 4) * 8;
    short8 vh, vl;
    #pragma unroll
    for (int j = 0; j < 8; ++j) {
      unsigned short hi, lo; splitf(W1s[(k0 + j) * 132 + col], hi, lo);
      vh[j] = (short)hi; vl[j] = (short)lo;
    }
    const size_t o = (((size_t)n * 8 + mt) * 2 + c2) * 512 + (size_t)ll * 8;
    *(short8*)(W1pHi + o) = vh;
    *(short8*)(W1pLo + o) = vl;
  }

  // phase 6 (blocks 0-2): fragment-pack conn[n] (A-frags, bf16-exact 0/1)
  if (n < 3) {
    #pragma unroll
    for (int rep = 0; rep < 8; ++rep) {
      const int slot = rep * 256 + t;            // 2048 lane-slots
      const int rt = slot >> 8, kc = (slot >> 6) & 3, ll = slot & 63;
      const int i = rt * 16 + (ll & 15), j0 = kc * 32 + (ll >> 4) * 8;
      const float* cp = conn + (size_t)n * 16384 + i * 128 + j0;
      float cv[8];
      ld4(cv, cp); ld4(cv + 4, cp + 4);
      short8 v;
      #pragma unroll
      for (int j = 0; j < 8; ++j)
        v[j] = (short)(__float_as_uint(cv[j]) >> 16);   // 0.0/1.0 exact
      *(short8*)(connP + (((size_t)(n * 8 + rt)) * 4 + kc) * 512 + (size_t)ll * 8) = v;
    }
  }
}

// ---------------------------------------------------------------------------
// Kernel A (r11 structure: 1 b-tile/wave, LDS-staged weights) with hardened
// numerics: fp32 x input (split on load), fp32 md output, and TWO-PASS LN
// variance sum((v-mu)^2) — no E[x^2]-mu^2 cancellation, so build-dependent
// FP-contraction cannot amplify (root cause of r8/r11/r12 absmax volatility).
// ---------------------------------------------------------------------------
__global__ __launch_bounds__(256)
void k_mlp(const float* __restrict__ xin,
           const unsigned short* __restrict__ W1pHi, const unsigned short* __restrict__ W1pLo,
           const float* __restrict__ b1, const float* __restrict__ lng,
           const float* __restrict__ lnb,
           const unsigned short* __restrict__ WfpHi, const unsigned short* __restrict__ WfpLo,
           const float* __restrict__ bfold, unsigned* __restrict__ mdP) {
  // [0,32KB): weight frags (hi @0, lo @16KB); later mdL overlays (17.4KB).
  // +448 u32 = 1792B bias region (b1[128], lng[128], lnb[128], bfold[64]).
  __shared__ __align__(16) unsigned ldsbuf[8192 + 448];
  float* bS = (float*)(ldsbuf + 8192);

  const int t = threadIdx.x;
  const int w = t >> 6, l = t & 63;
  const int bhat = l & 15, lg = l >> 4, kb = lg * 8;
  // XCD-bijective block swizzle: 4096 blocks, 8 XCDs -> 16 contiguous nodes/XCD
  const int wg = blockIdx.x;
  const int n  = (wg & 7) * 16 + ((wg >> 3) >> 5);
  const int b0 = ((wg >> 3) & 31) * 64;
  const int brow = b0 + w * 16 + bhat;         // this lane's batch row

  // ---- stage W1 frags + biases; coalesced uint4 copies ----
  {
    const uint4* whG = (const uint4*)(W1pHi + (size_t)n * 8192);
    const uint4* wlG = (const uint4*)(W1pLo + (size_t)n * 8192);
    uint4* lp = (uint4*)ldsbuf;
    #pragma unroll
    for (int i = 0; i < 4; ++i) {
      const int u4 = t + i * 256;              // 0..1023
      lp[u4]        = whG[u4];
      lp[1024 + u4] = wlG[u4];
    }
    if (t < 128) {
      bS[t]       = b1[n * Hh + t];
      bS[128 + t] = lng[n * Hh + t];
      bS[256 + t] = lnb[n * Hh + t];
    } else if (t < 192) {
      bS[384 + (t - 128)] = bfold[n * Dd + (t - 128)];
    }
  }

  // ---- x B-fragments: fp32 load + split (overlaps staging latency) ----
  short8 xhi[2], xlo[2];                       // [c2]
  {
    const float* xr = xin + ((size_t)brow * Nn + n) * Dd;
    #pragma unroll
    for (int c2 = 0; c2 < 2; ++c2) {
      const float4 p0 = *(const float4*)(xr + c2 * 32 + kb);
      const float4 p1 = *(const float4*)(xr + c2 * 32 + kb + 4);
      const float vv[8] = {p0.x, p0.y, p0.z, p0.w, p1.x, p1.y, p1.z, p1.w};
      #pragma unroll
      for (int j = 0; j < 8; ++j) {
        unsigned short hi, lo; splitf(vv[j], hi, lo);
        xhi[c2][j] = (short)hi; xlo[c2][j] = (short)lo;
      }
    }
  }
  __syncthreads();

  const unsigned short* lw = (const unsigned short*)ldsbuf;

  // ---- GEMM1: acc[mt]; 4-term split product, smallest term first ----
  f32x4 acc[8];
  #pragma unroll
  for (int mt = 0; mt < 8; ++mt) {
    float b4[4]; ld4(b4, bS + mt * 16 + lg * 4);
    acc[mt] = (f32x4){b4[0], b4[1], b4[2], b4[3]};
  }
  #pragma unroll
  for (int mt = 0; mt < 8; ++mt) {
    #pragma unroll
    for (int c2 = 0; c2 < 2; ++c2) {
      const int fo = (mt * 2 + c2) * 512;      // u16 units; imm offset in ds_read
      const short8 ah = *(const short8*)(lw + fo + l * 8);
      const short8 al = *(const short8*)(lw + 8192 + fo + l * 8);
      acc[mt] = __builtin_amdgcn_mfma_f32_16x16x32_bf16(al, xlo[c2], acc[mt], 0, 0, 0);
      acc[mt] = __builtin_amdgcn_mfma_f32_16x16x32_bf16(al, xhi[c2], acc[mt], 0, 0, 0);
      acc[mt] = __builtin_amdgcn_mfma_f32_16x16x32_bf16(ah, xlo[c2], acc[mt], 0, 0, 0);
      acc[mt] = __builtin_amdgcn_mfma_f32_16x16x32_bf16(ah, xhi[c2], acc[mt], 0, 0, 0);
    }
  }
  __syncthreads();                             // all waves done reading W1 frags

  // ---- restage: Wf frags into the same region ----
  {
    const uint4* fhG = (const uint4*)(WfpHi + (size_t)n * 8192);
    const uint4* flG = (const uint4*)(WfpLo + (size_t)n * 8192);
    uint4* lp = (uint4*)ldsbuf;
    #pragma unroll
    for (int i = 0; i < 4; ++i) {
      const int u4 = t + i * 256;
      lp[u4]        = fhG[u4];
      lp[1024 + u4] = flG[u4];
    }
  }

  // ---- LayerNorm stats, TWO-PASS (cancellation-free; overlaps restage) ----
  float sm = 0.f;
  #pragma unroll
  for (int mt = 0; mt < 8; ++mt)
    #pragma unroll
    for (int r = 0; r < 4; ++r) sm += acc[mt][r];
  sm += __shfl_xor(sm, 16);
  sm += __shfl_xor(sm, 32);
  const float mu = sm * (1.f / Hh);
  float sq = 0.f;
  #pragma unroll
  for (int mt = 0; mt < 8; ++mt)
    #pragma unroll
    for (int r = 0; r < 4; ++r) { const float dv = acc[mt][r] - mu; sq = fmaf(dv, dv, sq); }
  sq += __shfl_xor(sq, 16);
  sq += __shfl_xor(sq, 32);
  const float rs = rsqrtf(sq * (1.f / Hh) + 1e-5f);
  __syncthreads();

  // ---- GEMM2 (fused): per kc build Hg B-frag in-register, 4-term products ----
  f32x4 acc2[4];
  #pragma unroll
  for (int ft = 0; ft < 4; ++ft) {
    float b4[4]; ld4(b4, bS + 384 + ft * 16 + lg * 4);
    acc2[ft] = (f32x4){b4[0], b4[1], b4[2], b4[3]};
  }
  #pragma unroll
  for (int kc = 0; kc < 4; ++kc) {
    short8 hh, hl;
    #pragma unroll
    for (int half = 0; half < 2; ++half) {
      const int mt = kc * 2 + half;
      float g4[4], bb4[4];
      ld4(g4,  bS + 128 + mt * 16 + lg * 4);
      ld4(bb4, bS + 256 + mt * 16 + lg * 4);
      #pragma unroll
      for (int r = 0; r < 4; ++r) {
        const float v = gelu_exact((acc[mt][r] - mu) * rs * g4[r] + bb4[r]);
        unsigned short hi, lo; splitf(v, hi, lo);
        hh[half * 4 + r] = (short)hi;
        hl[half * 4 + r] = (short)lo;
      }
    }
    #pragma unroll
    for (int ft = 0; ft < 4; ++ft) {
      const int fo = (ft * 4 + kc) * 512;
      const short8 fh = *(const short8*)(lw + fo + l * 8);
      const short8 fl = *(const short8*)(lw + 8192 + fo + l * 8);
      acc2[ft] = __builtin_amdgcn_mfma_f32_16x16x32_bf16(fl, hl, acc2[ft], 0, 0, 0);
      acc2[ft] = __builtin_amdgcn_mfma_f32_16x16x32_bf16(fl, hh, acc2[ft], 0, 0, 0);
      acc2[ft] = __builtin_amdgcn_mfma_f32_16x16x32_bf16(fh, hl, acc2[ft], 0, 0, 0);
      acc2[ft] = __builtin_amdgcn_mfma_f32_16x16x32_bf16(fh, hh, acc2[ft], 0, 0, 0);
    }
  }
  __syncthreads();                             // done reading Wf frags

  // ---- md store: fp32 bits through per-wave LDS transpose ----
  unsigned* mw = ldsbuf + w * (16 * 68);
  #pragma unroll
  for (int ft = 0; ft < 4; ++ft) {
    unsigned q[4];
    #pragma unroll
    for (int r = 0; r < 4; ++r) q[r] = __float_as_uint(acc2[ft][r]);
    *(uint4*)&mw[bhat * 68 + ft * 16 + lg * 4] = *(const uint4*)q;
  }
  __syncthreads();
  #pragma unroll
  for (int i = 0; i < 4; ++i) {
    const int row = i * 4 + lg;                // local batch row 0..15
    const uint4 v = *(const uint4*)&mw[row * 68 + bhat * 4];
    *(uint4*)&mdP[((size_t)(b0 + w * 16 + row) * Nn + n) * Dd + bhat * 4] = v;
  }
}

// ---------------------------------------------------------------------------
// Kernel B (MFMA): x[b] = conn @ md[b] + decb.  md is now fp32; split to
// packed u32(hi|lo) ONCE per element while staging into tl (same layout).
// Always writes fp32 x to d_out.
// ---------------------------------------------------------------------------
__global__ __launch_bounds__(256)
void k_conn(const float* __restrict__ mdf, const unsigned short* __restrict__ connP,
            const float* __restrict__ decb, float* __restrict__ xout) {
  __shared__ unsigned tl[128 * 65];            // 33.3 KB
  const int b = blockIdx.x, t = threadIdx.x;
  const int w = t >> 6, l = t & 63, lr = l & 15, lg = l >> 4;

  // stage md[b]: fp32 load -> splitf -> packed u32, layout tl[j*65 + e]
  const float* mb = mdf + (size_t)b * (Nn * Dd);
  #pragma unroll
  for (int i = 0; i < 8; ++i) {
    const int fi = t + i * 256;                // float4 index 0..2047
    const int j = fi >> 4, e0 = (fi & 15) * 4;
    const float4 v = *(const float4*)(mb + (size_t)fi * 4);
    unsigned* dp = &tl[j * 65 + e0];
    unsigned short h_, l_;
    splitf(v.x, h_, l_); dp[0] = ((unsigned)h_ << 16) | l_;
    splitf(v.y, h_, l_); dp[1] = ((unsigned)h_ << 16) | l_;
    splitf(v.z, h_, l_); dp[2] = ((unsigned)h_ << 16) | l_;
    splitf(v.w, h_, l_); dp[3] = ((unsigned)h_ << 16) | l_;
  }
  __syncthreads();

  f32x4 acc[2][4];
  #pragma unroll
  for (int et = 0; et < 4; ++et) {
    const float dv = decb[et * 16 + lr];
    acc[0][et] = (f32x4){dv, dv, dv, dv};
    acc[1][et] = acc[0][et];
  }

  #pragma unroll
  for (int kc = 0; kc < 4; ++kc) {
    const short8 a0 = *(const short8*)(connP + ((size_t)(w * 2 + 0) * 4 + kc) * 512 + (size_t)l * 8);
    const short8 a1 = *(const short8*)(connP + ((size_t)(w * 2 + 1) * 4 + kc) * 512 + (size_t)l * 8);
    #pragma unroll
    for (int et = 0; et < 4; ++et) {
      const unsigned* tp = &tl[(kc * 32 + lg * 8) * 65 + et * 16 + lr];
      unsigned u[8];
      #pragma unroll
      for (int j = 0; j < 8; ++j) u[j] = tp[j * 65];
      short8 bh, bl;
      #pragma unroll
      for (int j = 0; j < 8; ++j) {
        bh[j] = (short)(u[j] >> 16);
        bl[j] = (short)(u[j] & 0xffffu);
      }
      acc[0][et] = __builtin_amdgcn_mfma_f32_16x16x32_bf16(a0, bl, acc[0][et], 0, 0, 0);
      acc[1][et] = __builtin_amdgcn_mfma_f32_16x16x32_bf16(a1, bl, acc[1][et], 0, 0, 0);
      acc[0][et] = __builtin_amdgcn_mfma_f32_16x16x32_bf16(a0, bh, acc[0][et], 0, 0, 0);
      acc[1][et] = __builtin_amdgcn_mfma_f32_16x16x32_bf16(a1, bh, acc[1][et], 0, 0, 0);
    }
  }

  #pragma unroll
  for (int rt = 0; rt < 2; ++rt) {
    #pragma unroll
    for (int et = 0; et < 4; ++et) {
      #pragma unroll
      for (int r = 0; r < 4; ++r) {
        const int i = w * 32 + rt * 16 + lg * 4 + r;
        const int e = et * 16 + lr;
        xout[((size_t)b * Nn + i) * Dd + e] = acc[rt][et][r];
      }
    }
  }
}

extern "C" void kernel_launch(void* const* d_in, const int* in_sizes, int n_in,
                              void* d_out, int out_size, void* d_ws, size_t ws_size,
                              hipStream_t stream) {
  const float* x0   = (const float*)d_in[0];
  const float* W1   = (const float*)d_in[1];
  const float* b1   = (const float*)d_in[2];
  const float* lng  = (const float*)d_in[3];
  const float* lnb  = (const float*)d_in[4];
  const float* W2   = (const float*)d_in[5];
  const float* b2   = (const float*)d_in[6];
  const float* encW = (const float*)d_in[7];
  const float* encb = (const float*)d_in[8];
  const float* decW = (const float*)d_in[9];
  const float* decb = (const float*)d_in[10];
  const float* conn = (const float*)d_in[11];

  char* ws = (char*)d_ws;
  unsigned* mdP = (unsigned*)ws;                        // 64 MB (fp32 bits)
  size_t off = 64ull << 20;
  unsigned short* W1pHi = (unsigned short*)(ws + off); off += 2ull << 20;
  unsigned short* W1pLo = (unsigned short*)(ws + off); off += 2ull << 20;
  unsigned short* WfpHi = (unsigned short*)(ws + off); off += 2ull << 20;
  unsigned short* WfpLo = (unsigned short*)(ws + off); off += 2ull << 20;
  float* bfold = (float*)(ws + off); off += 128 * 64 * 4;
  unsigned short* connP = (unsigned short*)(ws + off); off += 3ull * 16384 * 2;

  float* xbuf = (float*)d_out;                 // fp32 x ping-pongs through d_out

  k_prep<<<Nn, 256, 0, stream>>>(W1, W2, b2, encW, encb, decW, conn,
                                 W1pHi, W1pLo, WfpHi, WfpLo, bfold, connP);

  for (int d = 0; d < 3; ++d) {
    const float* xi = (d == 0) ? x0 : xbuf;
    k_mlp<<<4096, 256, 0, stream>>>(xi, W1pHi, W1pLo, b1, lng, lnb,
                                    WfpHi, WfpLo, bfold, mdP);
    k_conn<<<Bb, 256, 0, stream>>>((const float*)mdP, connP + (size_t)d * 16384,
                                   decb, xbuf);
  }
}

// Round 14
// 246.057 us; speedup vs baseline: 1.0336x; 1.0053x over previous
//
#include <hip/hip_runtime.h>
#include <cmath>

#define Bb 2048
#define Nn 128
#define Dd 64
#define Hh 128

typedef __attribute__((ext_vector_type(8))) short short8;
typedef __attribute__((ext_vector_type(4))) float f32x4;

typedef union { short8 s8; unsigned u[4]; } fragu;

__device__ __forceinline__ void ld4(float* d, const float* s) {
  const float4 v = *(const float4*)s;
  d[0] = v.x; d[1] = v.y; d[2] = v.z; d[3] = v.w;
}
__device__ __forceinline__ void st4(float* d, const float* s) {
  *(float4*)d = make_float4(s[0], s[1], s[2], s[3]);
}

// Scalar 2-way bf16 split (prep/conn paths): hi = round-half-up bf16, lo = RNE
// bf16 of residual. With the lo*lo MFMA term: split-product error ~2^-18.
__device__ __forceinline__ void splitf(float v, unsigned short& hi, unsigned short& lo) {
  const unsigned up = __float_as_uint(v) + 0x8000u;
  hi = (unsigned short)(up >> 16);
  const float hif = __uint_as_float(up & 0xffff0000u);
  unsigned ur = __float_as_uint(v - hif);
  ur += 0x7fffu + ((ur >> 16) & 1u);           // RNE
  lo = (unsigned short)(ur >> 16);
}

// HW-packed pair split: v_cvt_pk_bf16_f32 packs D[15:0]=bf16(S0),
// D[31:16]=bf16(S1), RNE. Produces the hi-word and lo-word for elements
// (2k, 2k+1) of a fragment directly — no u16 insertion ops.
__device__ __forceinline__ void splitf2(float v0, float v1, unsigned& h, unsigned& lo) {
  asm("v_cvt_pk_bf16_f32 %0, %1, %2" : "=v"(h) : "v"(v0), "v"(v1));
  const float h0 = __uint_as_float(h << 16);
  const float h1 = __uint_as_float(h & 0xffff0000u);
  asm("v_cvt_pk_bf16_f32 %0, %1, %2" : "=v"(lo) : "v"(v0 - h0), "v"(v1 - h1));
}

// Branch-free exact-GELU via Abramowitz-Stegun 7.1.26 (|erf err| <= 1.5e-7).
__device__ __forceinline__ float gelu_exact(float v) {
  const float s  = fabsf(v) * 0.70710678118654752f;
  const float tt = __builtin_amdgcn_rcpf(fmaf(0.3275911f, s, 1.0f));
  float p = fmaf(tt, 1.061405429f, -1.453152027f);
  p = fmaf(tt, p, 1.421413741f);
  p = fmaf(tt, p, -0.284496736f);
  p = fmaf(tt, p, 0.254829592f);
  p = p * tt;
  const float E  = exp2f(s * s * -1.44269504088896f);
  const float er = fmaf(-p, E, 1.0f);
  const float es = copysignf(er, v);
  return v * fmaf(0.5f, es, 0.5f);
}

// ---------------------------------------------------------------------------
// k_prep (grid Nn): fold enc/dec; fragment-pack W1 (A-frag, plain k-order) and
// Wfold (A-frag, PERMUTED k-order matching register-resident Hg B-frags);
// blocks 0-2 fragment-pack conn[d] (bf16-exact 0/1).  [identical to r13]
// ---------------------------------------------------------------------------
__global__ __launch_bounds__(256)
void k_prep(const float* __restrict__ W1, const float* __restrict__ W2,
            const float* __restrict__ b2, const float* __restrict__ encW,
            const float* __restrict__ encb, const float* __restrict__ decW,
            const float* __restrict__ conn,
            unsigned short* __restrict__ W1pHi, unsigned short* __restrict__ W1pLo,
            unsigned short* __restrict__ WfpHi, unsigned short* __restrict__ WfpLo,
            float* __restrict__ bfold, unsigned short* __restrict__ connP) {
  __shared__ float sm[26112];                  // 104.4 KB
  float* decS = sm;                            // [64][68]
  float* E2s  = sm + 4352;                     // [64][68]
  float* W2s  = sm + 8704;                     // [128][68]
  float* Wfs  = sm + 17408;                    // [128][68]
  float* W1s  = sm;                            // [64][132] overlays decS+E2s
  const int n = blockIdx.x, t = threadIdx.x;

  // phase 1: stage decW, W2[n]
  #pragma unroll
  for (int i = 0; i < 4; ++i) {
    const int fi = t + i * 256;
    *(float4*)&decS[(fi >> 4) * 68 + (fi & 15) * 4] = *(const float4*)(decW + fi * 4);
  }
  #pragma unroll
  for (int i = 0; i < 8; ++i) {
    const int fi = t + i * 256;
    *(float4*)&W2s[(fi >> 4) * 68 + (fi & 15) * 4] =
        *(const float4*)(W2 + (size_t)n * 8192 + fi * 4);
  }
  __syncthreads();

  // phase 2: E2 = encW @ decW
  {
    const int d = t >> 2, f0 = (t & 3) * 16;
    float acc[16];
    #pragma unroll
    for (int ff = 0; ff < 16; ++ff) acc[ff] = 0.f;
    for (int e = 0; e < 64; ++e) {
      const float a = encW[d * 64 + e];
      #pragma unroll
      for (int ff = 0; ff < 16; ++ff) acc[ff] += a * decS[e * 68 + f0 + ff];
    }
    #pragma unroll
    for (int q = 0; q < 4; ++q) st4(&E2s[d * 68 + f0 + q * 4], &acc[q * 4]);
  }
  __syncthreads();

  // phase 3: Wfs = W2s @ E2s; bfold
  {
    const int h = t >> 1, f0 = (t & 1) * 32;
    float acc[32];
    #pragma unroll
    for (int ff = 0; ff < 32; ++ff) acc[ff] = 0.f;
    for (int d2 = 0; d2 < 64; ++d2) {
      const float a = W2s[h * 68 + d2];
      #pragma unroll
      for (int q = 0; q < 8; ++q) {
        float e4[4]; ld4(e4, &E2s[d2 * 68 + f0 + q * 4]);
        #pragma unroll
        for (int r = 0; r < 4; ++r) acc[q * 4 + r] += a * e4[r];
      }
    }
    #pragma unroll
    for (int q = 0; q < 8; ++q) st4(&Wfs[h * 68 + f0 + q * 4], &acc[q * 4]);
  }
  if (t < 64) {
    float s = 0.f;
    for (int e = 0; e < 64; ++e) s += encb[e] * decS[e * 68 + t];
    for (int d2 = 0; d2 < 64; ++d2) s += b2[n * 64 + d2] * E2s[d2 * 68 + t];
    bfold[n * 64 + t] = s;
  }
  __syncthreads();

  // phase 4: pack Wfs -> Wfp (A-frag with PERMUTED k); stage W1 -> W1s
  #pragma unroll
  for (int rep = 0; rep < 4; ++rep) {
    const int idx = rep * 256 + t;
    const int ft = idx >> 8, kc = (idx >> 6) & 3, ll = idx & 63;
    const int f = ft * 16 + (ll & 15);
    short8 vh, vl;
    #pragma unroll
    for (int j = 0; j < 8; ++j) {
      const int hcol = kc * 32 + ((j >> 2) << 4) + ((ll >> 4) << 2) + (j & 3);
      unsigned short hi, lo; splitf(Wfs[hcol * 68 + f], hi, lo);
      vh[j] = (short)hi; vl[j] = (short)lo;
    }
    const size_t o = (((size_t)n * 4 + ft) * 4 + kc) * 512 + (size_t)ll * 8;
    *(short8*)(WfpHi + o) = vh;
    *(short8*)(WfpLo + o) = vl;
  }
  #pragma unroll
  for (int i = 0; i < 8; ++i) {
    const int fi = t + i * 256;
    *(float4*)&W1s[(fi >> 5) * 132 + (fi & 31) * 4] =
        *(const float4*)(W1 + (size_t)n * 8192 + fi * 4);
  }
  __syncthreads();

  // phase 5: pack W1s -> W1p (A-frag, plain k-order)
  #pragma unroll
  for (int rep = 0; rep < 4; ++rep) {
    const int idx = rep * 256 + t;
    const int mt = idx >> 7, c2 = (idx >> 6) & 1, ll = idx & 63;
    const int col = mt * 16 + (ll & 15), k0 = c2 * 32 + (ll >> 4) * 8;
    short8 vh, vl;
    #pragma unroll
    for (int j = 0; j < 8; ++j) {
      unsigned short hi, lo; splitf(W1s[(k0 + j) * 132 + col], hi, lo);
      vh[j] = (short)hi; vl[j] = (short)lo;
    }
    const size_t o = (((size_t)n * 8 + mt) * 2 + c2) * 512 + (size_t)ll * 8;
    *(short8*)(W1pHi + o) = vh;
    *(short8*)(W1pLo + o) = vl;
  }

  // phase 6 (blocks 0-2): fragment-pack conn[n] (A-frags, bf16-exact 0/1)
  if (n < 3) {
    #pragma unroll
    for (int rep = 0; rep < 8; ++rep) {
      const int slot = rep * 256 + t;            // 2048 lane-slots
      const int rt = slot >> 8, kc = (slot >> 6) & 3, ll = slot & 63;
      const int i = rt * 16 + (ll & 15), j0 = kc * 32 + (ll >> 4) * 8;
      const float* cp = conn + (size_t)n * 16384 + i * 128 + j0;
      float cv[8];
      ld4(cv, cp); ld4(cv + 4, cp + 4);
      short8 v;
      #pragma unroll
      for (int j = 0; j < 8; ++j)
        v[j] = (short)(__float_as_uint(cv[j]) >> 16);   // 0.0/1.0 exact
      *(short8*)(connP + (((size_t)(n * 8 + rt)) * 4 + kc) * 512 + (size_t)ll * 8) = v;
    }
  }
}

// ---------------------------------------------------------------------------
// Kernel A (r13 structure + HW-packed bf16 splits): 1 b-tile/wave, LDS-staged
// weights, two-pass LN, fp32 x in / fp32 md out. x-split and Hg-split now use
// v_cvt_pk_bf16_f32 pairs writing fragment u32 words directly (~6 ops per 2
// elements' hi+lo vs ~18 scalar, and zero u16-insertion ops).
// ---------------------------------------------------------------------------
__global__ __launch_bounds__(256)
void k_mlp(const float* __restrict__ xin,
           const unsigned short* __restrict__ W1pHi, const unsigned short* __restrict__ W1pLo,
           const float* __restrict__ b1, const float* __restrict__ lng,
           const float* __restrict__ lnb,
           const unsigned short* __restrict__ WfpHi, const unsigned short* __restrict__ WfpLo,
           const float* __restrict__ bfold, unsigned* __restrict__ mdP) {
  // [0,32KB): weight frags (hi @0, lo @16KB); later mdL overlays (17.4KB).
  // +448 u32 = 1792B bias region (b1[128], lng[128], lnb[128], bfold[64]).
  __shared__ __align__(16) unsigned ldsbuf[8192 + 448];
  float* bS = (float*)(ldsbuf + 8192);

  const int t = threadIdx.x;
  const int w = t >> 6, l = t & 63;
  const int bhat = l & 15, lg = l >> 4, kb = lg * 8;
  // XCD-bijective block swizzle: 4096 blocks, 8 XCDs -> 16 contiguous nodes/XCD
  const int wg = blockIdx.x;
  const int n  = (wg & 7) * 16 + ((wg >> 3) >> 5);
  const int b0 = ((wg >> 3) & 31) * 64;
  const int brow = b0 + w * 16 + bhat;         // this lane's batch row

  // ---- stage W1 frags + biases; coalesced uint4 copies ----
  {
    const uint4* whG = (const uint4*)(W1pHi + (size_t)n * 8192);
    const uint4* wlG = (const uint4*)(W1pLo + (size_t)n * 8192);
    uint4* lp = (uint4*)ldsbuf;
    #pragma unroll
    for (int i = 0; i < 4; ++i) {
      const int u4 = t + i * 256;              // 0..1023
      lp[u4]        = whG[u4];
      lp[1024 + u4] = wlG[u4];
    }
    if (t < 128) {
      bS[t]       = b1[n * Hh + t];
      bS[128 + t] = lng[n * Hh + t];
      bS[256 + t] = lnb[n * Hh + t];
    } else if (t < 192) {
      bS[384 + (t - 128)] = bfold[n * Dd + (t - 128)];
    }
  }

  // ---- x B-fragments: fp32 load + packed split (overlaps staging latency) ----
  fragu xhi[2], xlo[2];                        // [c2]
  {
    const float* xr = xin + ((size_t)brow * Nn + n) * Dd;
    #pragma unroll
    for (int c2 = 0; c2 < 2; ++c2) {
      const float4 p0 = *(const float4*)(xr + c2 * 32 + kb);
      const float4 p1 = *(const float4*)(xr + c2 * 32 + kb + 4);
      splitf2(p0.x, p0.y, xhi[c2].u[0], xlo[c2].u[0]);
      splitf2(p0.z, p0.w, xhi[c2].u[1], xlo[c2].u[1]);
      splitf2(p1.x, p1.y, xhi[c2].u[2], xlo[c2].u[2]);
      splitf2(p1.z, p1.w, xhi[c2].u[3], xlo[c2].u[3]);
    }
  }
  __syncthreads();

  const unsigned short* lw = (const unsigned short*)ldsbuf;

  // ---- GEMM1: acc[mt]; 4-term split product, smallest term first ----
  f32x4 acc[8];
  #pragma unroll
  for (int mt = 0; mt < 8; ++mt) {
    float b4[4]; ld4(b4, bS + mt * 16 + lg * 4);
    acc[mt] = (f32x4){b4[0], b4[1], b4[2], b4[3]};
  }
  #pragma unroll
  for (int mt = 0; mt < 8; ++mt) {
    #pragma unroll
    for (int c2 = 0; c2 < 2; ++c2) {
      const int fo = (mt * 2 + c2) * 512;      // u16 units; imm offset in ds_read
      const short8 ah = *(const short8*)(lw + fo + l * 8);
      const short8 al = *(const short8*)(lw + 8192 + fo + l * 8);
      acc[mt] = __builtin_amdgcn_mfma_f32_16x16x32_bf16(al, xlo[c2].s8, acc[mt], 0, 0, 0);
      acc[mt] = __builtin_amdgcn_mfma_f32_16x16x32_bf16(al, xhi[c2].s8, acc[mt], 0, 0, 0);
      acc[mt] = __builtin_amdgcn_mfma_f32_16x16x32_bf16(ah, xlo[c2].s8, acc[mt], 0, 0, 0);
      acc[mt] = __builtin_amdgcn_mfma_f32_16x16x32_bf16(ah, xhi[c2].s8, acc[mt], 0, 0, 0);
    }
  }
  __syncthreads();                             // all waves done reading W1 frags

  // ---- restage: Wf frags into the same region ----
  {
    const uint4* fhG = (const uint4*)(WfpHi + (size_t)n * 8192);
    const uint4* flG = (const uint4*)(WfpLo + (size_t)n * 8192);
    uint4* lp = (uint4*)ldsbuf;
    #pragma unroll
    for (int i = 0; i < 4; ++i) {
      const int u4 = t + i * 256;
      lp[u4]        = fhG[u4];
      lp[1024 + u4] = flG[u4];
    }
  }

  // ---- LayerNorm stats, TWO-PASS (cancellation-free; overlaps restage) ----
  float sm = 0.f;
  #pragma unroll
  for (int mt = 0; mt < 8; ++mt)
    #pragma unroll
    for (int r = 0; r < 4; ++r) sm += acc[mt][r];
  sm += __shfl_xor(sm, 16);
  sm += __shfl_xor(sm, 32);
  const float mu = sm * (1.f / Hh);
  float sq = 0.f;
  #pragma unroll
  for (int mt = 0; mt < 8; ++mt)
    #pragma unroll
    for (int r = 0; r < 4; ++r) { const float dv = acc[mt][r] - mu; sq = fmaf(dv, dv, sq); }
  sq += __shfl_xor(sq, 16);
  sq += __shfl_xor(sq, 32);
  const float rs = rsqrtf(sq * (1.f / Hh) + 1e-5f);
  __syncthreads();

  // ---- GEMM2 (fused): per kc build Hg B-frag in-register (packed split),
  //      then 4 ft x 4-term MFMA products ----
  f32x4 acc2[4];
  #pragma unroll
  for (int ft = 0; ft < 4; ++ft) {
    float b4[4]; ld4(b4, bS + 384 + ft * 16 + lg * 4);
    acc2[ft] = (f32x4){b4[0], b4[1], b4[2], b4[3]};
  }
  #pragma unroll
  for (int kc = 0; kc < 4; ++kc) {
    fragu hh, hl;
    #pragma unroll
    for (int half = 0; half < 2; ++half) {
      const int mt = kc * 2 + half;
      float g4[4], bb4[4];
      ld4(g4,  bS + 128 + mt * 16 + lg * 4);
      ld4(bb4, bS + 256 + mt * 16 + lg * 4);
      float v[4];
      #pragma unroll
      for (int r = 0; r < 4; ++r)
        v[r] = gelu_exact((acc[mt][r] - mu) * rs * g4[r] + bb4[r]);
      splitf2(v[0], v[1], hh.u[half * 2],     hl.u[half * 2]);
      splitf2(v[2], v[3], hh.u[half * 2 + 1], hl.u[half * 2 + 1]);
    }
    #pragma unroll
    for (int ft = 0; ft < 4; ++ft) {
      const int fo = (ft * 4 + kc) * 512;
      const short8 fh = *(const short8*)(lw + fo + l * 8);
      const short8 fl = *(const short8*)(lw + 8192 + fo + l * 8);
      acc2[ft] = __builtin_amdgcn_mfma_f32_16x16x32_bf16(fl, hl.s8, acc2[ft], 0, 0, 0);
      acc2[ft] = __builtin_amdgcn_mfma_f32_16x16x32_bf16(fl, hh.s8, acc2[ft], 0, 0, 0);
      acc2[ft] = __builtin_amdgcn_mfma_f32_16x16x32_bf16(fh, hl.s8, acc2[ft], 0, 0, 0);
      acc2[ft] = __builtin_amdgcn_mfma_f32_16x16x32_bf16(fh, hh.s8, acc2[ft], 0, 0, 0);
    }
  }
  __syncthreads();                             // done reading Wf frags

  // ---- md store: fp32 bits through per-wave LDS transpose ----
  unsigned* mw = ldsbuf + w * (16 * 68);
  #pragma unroll
  for (int ft = 0; ft < 4; ++ft) {
    unsigned q[4];
    #pragma unroll
    for (int r = 0; r < 4; ++r) q[r] = __float_as_uint(acc2[ft][r]);
    *(uint4*)&mw[bhat * 68 + ft * 16 + lg * 4] = *(const uint4*)q;
  }
  __syncthreads();
  #pragma unroll
  for (int i = 0; i < 4; ++i) {
    const int row = i * 4 + lg;                // local batch row 0..15
    const uint4 v = *(const uint4*)&mw[row * 68 + bhat * 4];
    *(uint4*)&mdP[((size_t)(b0 + w * 16 + row) * Nn + n) * Dd + bhat * 4] = v;
  }
}

// ---------------------------------------------------------------------------
// Kernel B (MFMA): x[b] = conn @ md[b] + decb.  md is fp32; split to packed
// u32(hi|lo) once per element while staging into tl.  [identical to r13]
// ---------------------------------------------------------------------------
__global__ __launch_bounds__(256)
void k_conn(const float* __restrict__ mdf, const unsigned short* __restrict__ connP,
            const float* __restrict__ decb, float* __restrict__ xout) {
  __shared__ unsigned tl[128 * 65];            // 33.3 KB
  const int b = blockIdx.x, t = threadIdx.x;
  const int w = t >> 6, l = t & 63, lr = l & 15, lg = l >> 4;

  // stage md[b]: fp32 load -> splitf -> packed u32, layout tl[j*65 + e]
  const float* mb = mdf + (size_t)b * (Nn * Dd);
  #pragma unroll
  for (int i = 0; i < 8; ++i) {
    const int fi = t + i * 256;                // float4 index 0..2047
    const int j = fi >> 4, e0 = (fi & 15) * 4;
    const float4 v = *(const float4*)(mb + (size_t)fi * 4);
    unsigned* dp = &tl[j * 65 + e0];
    unsigned short h_, l_;
    splitf(v.x, h_, l_); dp[0] = ((unsigned)h_ << 16) | l_;
    splitf(v.y, h_, l_); dp[1] = ((unsigned)h_ << 16) | l_;
    splitf(v.z, h_, l_); dp[2] = ((unsigned)h_ << 16) | l_;
    splitf(v.w, h_, l_); dp[3] = ((unsigned)h_ << 16) | l_;
  }
  __syncthreads();

  f32x4 acc[2][4];
  #pragma unroll
  for (int et = 0; et < 4; ++et) {
    const float dv = decb[et * 16 + lr];
    acc[0][et] = (f32x4){dv, dv, dv, dv};
    acc[1][et] = acc[0][et];
  }

  #pragma unroll
  for (int kc = 0; kc < 4; ++kc) {
    const short8 a0 = *(const short8*)(connP + ((size_t)(w * 2 + 0) * 4 + kc) * 512 + (size_t)l * 8);
    const short8 a1 = *(const short8*)(connP + ((size_t)(w * 2 + 1) * 4 + kc) * 512 + (size_t)l * 8);
    #pragma unroll
    for (int et = 0; et < 4; ++et) {
      const unsigned* tp = &tl[(kc * 32 + lg * 8) * 65 + et * 16 + lr];
      unsigned u[8];
      #pragma unroll
      for (int j = 0; j < 8; ++j) u[j] = tp[j * 65];
      short8 bh, bl;
      #pragma unroll
      for (int j = 0; j < 8; ++j) {
        bh[j] = (short)(u[j] >> 16);
        bl[j] = (short)(u[j] & 0xffffu);
      }
      acc[0][et] = __builtin_amdgcn_mfma_f32_16x16x32_bf16(a0, bl, acc[0][et], 0, 0, 0);
      acc[1][et] = __builtin_amdgcn_mfma_f32_16x16x32_bf16(a1, bl, acc[1][et], 0, 0, 0);
      acc[0][et] = __builtin_amdgcn_mfma_f32_16x16x32_bf16(a0, bh, acc[0][et], 0, 0, 0);
      acc[1][et] = __builtin_amdgcn_mfma_f32_16x16x32_bf16(a1, bh, acc[1][et], 0, 0, 0);
    }
  }

  #pragma unroll
  for (int rt = 0; rt < 2; ++rt) {
    #pragma unroll
    for (int et = 0; et < 4; ++et) {
      #pragma unroll
      for (int r = 0; r < 4; ++r) {
        const int i = w * 32 + rt * 16 + lg * 4 + r;
        const int e = et * 16 + lr;
        xout[((size_t)b * Nn + i) * Dd + e] = acc[rt][et][r];
      }
    }
  }
}

extern "C" void kernel_launch(void* const* d_in, const int* in_sizes, int n_in,
                              void* d_out, int out_size, void* d_ws, size_t ws_size,
                              hipStream_t stream) {
  const float* x0   = (const float*)d_in[0];
  const float* W1   = (const float*)d_in[1];
  const float* b1   = (const float*)d_in[2];
  const float* lng  = (const float*)d_in[3];
  const float* lnb  = (const float*)d_in[4];
  const float* W2   = (const float*)d_in[5];
  const float* b2   = (const float*)d_in[6];
  const float* encW = (const float*)d_in[7];
  const float* encb = (const float*)d_in[8];
  const float* decW = (const float*)d_in[9];
  const float* decb = (const float*)d_in[10];
  const float* conn = (const float*)d_in[11];

  char* ws = (char*)d_ws;
  unsigned* mdP = (unsigned*)ws;                        // 64 MB (fp32 bits)
  size_t off = 64ull << 20;
  unsigned short* W1pHi = (unsigned short*)(ws + off); off += 2ull << 20;
  unsigned short* W1pLo = (unsigned short*)(ws + off); off += 2ull << 20;
  unsigned short* WfpHi = (unsigned short*)(ws + off); off += 2ull << 20;
  unsigned short* WfpLo = (unsigned short*)(ws + off); off += 2ull << 20;
  float* bfold = (float*)(ws + off); off += 128 * 64 * 4;
  unsigned short* connP = (unsigned short*)(ws + off); off += 3ull * 16384 * 2;

  float* xbuf = (float*)d_out;                 // fp32 x ping-pongs through d_out

  k_prep<<<Nn, 256, 0, stream>>>(W1, W2, b2, encW, encb, decW, conn,
                                 W1pHi, W1pLo, WfpHi, WfpLo, bfold, connP);

  for (int d = 0; d < 3; ++d) {
    const float* xi = (d == 0) ? x0 : xbuf;
    k_mlp<<<4096, 256, 0, stream>>>(xi, W1pHi, W1pLo, b1, lng, lnb,
                                    WfpHi, WfpLo, bfold, mdP);
    k_conn<<<Bb, 256, 0, stream>>>((const float*)mdP, connP + (size_t)d * 16384,
                                   decb, xbuf);
  }
}